// Round 7
// baseline (419.009 us; speedup 1.0000x reference)
//
#include <hip/hip_runtime.h>
#include <hip/hip_bf16.h>

typedef _Float16 f16x8 __attribute__((ext_vector_type(8)));
typedef float f32x4 __attribute__((ext_vector_type(4)));

#define MFMA16(a, b, c) __builtin_amdgcn_mfma_f32_16x16x32_f16(a, b, c, 0, 0, 0)

__device__ __forceinline__ void load_lds16(const void* g, void* l) {
  __builtin_amdgcn_global_load_lds(
      (__attribute__((address_space(1))) void*)g,
      (__attribute__((address_space(3))) void*)l, 16, 0, 0);
}

// ---------------- f32 -> f16 convert (8 elems / thread / iter) ----------------
__global__ __launch_bounds__(256) void k_cvt16(const float* __restrict__ in,
                                               _Float16* __restrict__ out, int n8) {
  int stride = gridDim.x * blockDim.x;
  for (int i = blockIdx.x * blockDim.x + threadIdx.x; i < n8; i += stride) {
    const float4* p = (const float4*)(in + (size_t)i * 8);
    float4 a = p[0], b = p[1];
    f16x8 v = {(_Float16)a.x, (_Float16)a.y, (_Float16)a.z, (_Float16)a.w,
               (_Float16)b.x, (_Float16)b.y, (_Float16)b.z, (_Float16)b.w};
    *(f16x8*)(out + (size_t)i * 8) = v;
  }
}

// ---------- transpose + convert: in[K][N] f32 -> out[N][K] f16, 64x64 tiles ----------
__global__ __launch_bounds__(256) void k_transpose(const float* __restrict__ in,
                                                   _Float16* __restrict__ out, int K, int N) {
  __shared__ float tile[64][65];
  int k0 = blockIdx.y * 64, n0 = blockIdx.x * 64;
  int t = threadIdx.x;
  {
    int nn = t & 63, kb = t >> 6;
#pragma unroll
    for (int i = 0; i < 16; ++i) {
      int kk = kb + i * 4;
      tile[kk][nn] = in[(size_t)(k0 + kk) * N + n0 + nn];
    }
  }
  __syncthreads();
  {
    int kk = t & 63, nb = t >> 6;
#pragma unroll
    for (int i = 0; i < 16; ++i) {
      int nn = nb + i * 4;
      out[(size_t)(n0 + nn) * K + k0 + kk] = (_Float16)tile[kk][nn];
    }
  }
}

// ---------------- K/V projection: ctxh[616][768] @ W^T -> heads ----------------
__global__ __launch_bounds__(64) void k_kvproj(const _Float16* __restrict__ ctxh,
                                               const _Float16* __restrict__ Wkt,
                                               const _Float16* __restrict__ Wvt,
                                               _Float16* __restrict__ Kg,
                                               _Float16* __restrict__ Vtg) {
  int mt = blockIdx.x, nt = blockIdx.y;
  int lane = threadIdx.x;
  int l15 = lane & 15, lhi = lane >> 4;
  int arow = mt * 16 + l15;
  if (arow > 615) arow = 615;  // clamp; masked at write
  const _Float16* ap = ctxh + (size_t)arow * 768 + lhi * 8;
  const _Float16* kp = Wkt + (size_t)(nt * 16 + l15) * 768 + lhi * 8;
  const _Float16* vp = Wvt + (size_t)(nt * 16 + l15) * 768 + lhi * 8;
  f32x4 ak = {0.f, 0.f, 0.f, 0.f}, av = {0.f, 0.f, 0.f, 0.f};
#pragma unroll 4
  for (int ks = 0; ks < 24; ++ks) {
    f16x8 a = *(const f16x8*)(ap + ks * 32);
    f16x8 bk = *(const f16x8*)(kp + ks * 32);
    f16x8 bv = *(const f16x8*)(vp + ks * 32);
    ak = MFMA16(a, bk, ak);
    av = MFMA16(a, bv, av);
  }
  int n = nt * 16 + l15, h = n >> 6, d = n & 63;
#pragma unroll
  for (int j = 0; j < 4; ++j) {
    int gm = mt * 16 + lhi * 4 + j;
    if (gm < 616) {
      int b = gm / 77, m = gm - b * 77;
      Kg[((size_t)(b * 16 + h) * 77 + m) * 64 + d] = (_Float16)ak[j];
      Vtg[((size_t)(b * 16 + h) * 64 + d) * 128 + m] = (_Float16)av[j];
    }
  }
}

// ---------------- attention: one block = one (b,h) x 64 query rows ----------------
__global__ __launch_bounds__(256) void k_attn(const _Float16* __restrict__ Qh,
                                              const _Float16* __restrict__ Kg,
                                              const _Float16* __restrict__ Vtg,
                                              _Float16* __restrict__ Out) {
  __shared__ __align__(16) char Kl[80 * 128];
  __shared__ __align__(16) char Vl[64 * 256];
  __shared__ __align__(16) char Pl[4 * 16 * 256];
  int bh = blockIdx.y, b = bh >> 4, h = bh & 15;
  int t = threadIdx.x, wid = t >> 6, lane = t & 63;
  int l15 = lane & 15, lhi = lane >> 4;

  const _Float16* Kgp = Kg + (size_t)bh * (77 * 64);
  const _Float16* Vgp = Vtg + (size_t)bh * (64 * 128);

  for (int idx = t; idx < 640; idx += 256) {
    int m = idx >> 3, c = (idx & 7) * 8;
    f16x8 v = {};
    if (m < 77) v = *(const f16x8*)(Kgp + m * 64 + c);
    *(f16x8*)(Kl + ((m * 128 + c * 2) ^ ((m & 7) << 4))) = v;
  }
  for (int idx = t; idx < 1024; idx += 256) {
    int d = idx >> 4, c = (idx & 15) * 8;
    f16x8 v = *(const f16x8*)(Vgp + d * 128 + c);
    *(f16x8*)(Vl + ((d * 256 + c * 2) ^ ((d & 7) << 4))) = v;
  }
  char* myP = Pl + wid * 4096;
#pragma unroll
  for (int i = 0; i < 4; ++i) *(f16x8*)(myP + lane * 64 + i * 16) = f16x8{};
  __syncthreads();

  int qrow = b * 4096 + blockIdx.x * 64 + wid * 16 + l15;
  const _Float16* qp = Qh + (size_t)qrow * 1024 + h * 64 + lhi * 8;
  f16x8 q0 = *(const f16x8*)qp;
  f16x8 q1 = *(const f16x8*)(qp + 32);

  float e[5][4];
  float mx[4] = {-1e30f, -1e30f, -1e30f, -1e30f};
#pragma unroll
  for (int ct = 0; ct < 5; ++ct) {
    int m = ct * 16 + l15;
    int d0b = lhi * 16;
    f16x8 k0 = *(const f16x8*)(Kl + ((m * 128 + d0b) ^ ((m & 7) << 4)));
    f16x8 k1 = *(const f16x8*)(Kl + ((m * 128 + 64 + d0b) ^ ((m & 7) << 4)));
    f32x4 acc = {0.f, 0.f, 0.f, 0.f};
    acc = MFMA16(q0, k0, acc);
    acc = MFMA16(q1, k1, acc);
    bool valid = m < 77;
#pragma unroll
    for (int j = 0; j < 4; ++j) {
      float v = valid ? acc[j] * 0.125f : -1e30f;
      e[ct][j] = v;
      mx[j] = fmaxf(mx[j], v);
    }
  }
#pragma unroll
  for (int off = 1; off < 16; off <<= 1)
#pragma unroll
    for (int j = 0; j < 4; ++j) mx[j] = fmaxf(mx[j], __shfl_xor(mx[j], off, 64));
  float sm[4] = {0.f, 0.f, 0.f, 0.f};
#pragma unroll
  for (int ct = 0; ct < 5; ++ct)
#pragma unroll
    for (int j = 0; j < 4; ++j) {
      float ev = __expf(e[ct][j] - mx[j]);
      e[ct][j] = ev;
      sm[j] += ev;
    }
#pragma unroll
  for (int off = 1; off < 16; off <<= 1)
#pragma unroll
    for (int j = 0; j < 4; ++j) sm[j] += __shfl_xor(sm[j], off, 64);
  float rs[4];
#pragma unroll
  for (int j = 0; j < 4; ++j) rs[j] = 1.0f / sm[j];

#pragma unroll
  for (int ct = 0; ct < 5; ++ct) {
    int m = ct * 16 + l15;
#pragma unroll
    for (int j = 0; j < 4; ++j) {
      int r = lhi * 4 + j;
      *(_Float16*)(myP + ((r * 256 + m * 2) ^ ((r & 7) << 4))) =
          (_Float16)(e[ct][j] * rs[j]);
    }
  }

  f32x4 o[4] = {{0.f,0.f,0.f,0.f},{0.f,0.f,0.f,0.f},{0.f,0.f,0.f,0.f},{0.f,0.f,0.f,0.f}};
#pragma unroll
  for (int ks = 0; ks < 3; ++ks) {
    int m0b = ks * 64 + lhi * 16;
    f16x8 pa = *(const f16x8*)(myP + ((l15 * 256 + m0b) ^ ((l15 & 7) << 4)));
#pragma unroll
    for (int dt = 0; dt < 4; ++dt) {
      int d = dt * 16 + l15;
      f16x8 vb = *(const f16x8*)(Vl + ((d * 256 + m0b) ^ ((d & 7) << 4)));
      o[dt] = MFMA16(pa, vb, o[dt]);
    }
  }
  _Float16* op = Out + (size_t)(b * 4096 + blockIdx.x * 64 + wid * 16) * 1024 + h * 64;
#pragma unroll
  for (int dt = 0; dt < 4; ++dt)
#pragma unroll
    for (int j = 0; j < 4; ++j) {
      int r = lhi * 4 + j;
      op[(size_t)r * 1024 + dt * 16 + l15] = (_Float16)o[dt][j];
    }
}

// ============ 256x256 GEMM, 8-phase (R5 structure) + R6-verified row&7 swizzle ======
// A [M][K] f16, Bt [N][K] f16. BK=64 (8 x 16B chunks/row), 512 thr = 8 waves (2Mx4N),
// per-wave C = 128x64 = 8 m-frags x 4 n-frags of 16x16. 4 phases per K-tile,
// 16 MFMA16 per phase (one C-quadrant).
// Swizzle (verified conflict-free in R6, SQ_LDS_BANK_CONFLICT==0): 16B chunk c of
// row r stored at chunk c ^ (r&7). Staging pre-swizzles the GLOBAL source chunk
// (linear LDS dest for global_load_lds); reads XOR the same on the LDS address.
// Fragment reads have row = 16*const + l15, so row&7 = l15&7 for every read.
// Staging calendar (2 gloads/phase, dests dead >=1 closing barrier before issue):
//   q0: A(t+1,{64,192})  q1: A(t+2,{0,128})  q2: B(t+2,{0,64})
//   q3: B(t+2,{128,192}); vmcnt(6); barrier publishes tile t+1
template <int FINAL>
__global__ __launch_bounds__(512, 2) void k_gemm5(const _Float16* __restrict__ A,
                                                  const _Float16* __restrict__ Bt,
                                                  void* __restrict__ Cout,
                                                  const float* __restrict__ bias,
                                                  int M, int N, int K) {
  __shared__ __align__(16) char lds[131072];
  const int t = threadIdx.x, wid = t >> 6, lane = t & 63;
  const int wr = wid >> 2, wc = wid & 3;  // 2M x 4N wave grid
  const int l15 = lane & 15, lhi = lane >> 4;

  // T1: bijective XCD swizzle (nwg % 8 == 0)
  int nwg = gridDim.x, bid = blockIdx.x;
  int wg = ((nwg & 7) == 0) ? ((bid & 7) * (nwg >> 3) + (bid >> 3)) : bid;
  const int nTN = N >> 8;
  const int tm = wg / nTN, tn = wg % nTN;

  const _Float16* Ag = A + (size_t)tm * 256 * K;
  const _Float16* Bg = Bt + (size_t)tn * 256 * K;
  // staging source: row = wid*8 + (lane>>3) (+slice; slices = 0 mod 8), source
  // chunk = destchunk ^ (row&7) = (lane&7) ^ ((lane>>3)&7)   [R6-verified]
  const size_t stg = (size_t)(wid * 8 + (lane >> 3)) * K +
                     (size_t)(((lane & 7) ^ ((lane >> 3) & 7)) * 8);
  const int dstg = wid * 1024;  // linear wave dest (HW adds lane*16)

  // read swizzle: chunk = (kk*4 + lhi) ^ (l15&7); kk=1 = address ^ 64 (chunk bit2)
  const int csw = ((lhi ^ (l15 & 7)) << 4);
  const int aoff = wr * 16384 + l15 * 128 + csw;         // + mh*8192 + mf*2048 (+^64 kk)
  const int boff = 32768 + wc * 8192 + l15 * 128 + csw;  // + nh*4096 + nf*2048 (+^64 kk)

  f32x4 acc[8][4];
#pragma unroll
  for (int i = 0; i < 8; ++i)
#pragma unroll
    for (int j = 0; j < 4; ++j) acc[i][j] = f32x4{0.f, 0.f, 0.f, 0.f};
  f16x8 a[4][2], b0[2][2], b1[2][2];

#define STG_A(T, RB) load_lds16(Ag + stg + (size_t)(RB) * K + (T) * 64, \
                                lds + ((T) & 1) * 65536 + (RB) * 128 + dstg)
#define STG_B(T, RB) load_lds16(Bg + stg + (size_t)(RB) * K + (T) * 64, \
                                lds + ((T) & 1) * 65536 + 32768 + (RB) * 128 + dstg)
#define RD_A(BUF, MH) { const char* p_ = lds + (BUF) * 65536 + aoff + (MH) * 8192;      \
    _Pragma("unroll") for (int mf = 0; mf < 4; ++mf) {                                  \
      a[mf][0] = *(const f16x8*)(p_ + mf * 2048);                                       \
      a[mf][1] = *(const f16x8*)((const char*)((size_t)(p_ + mf * 2048) ^ 64)); } }
#define RD_B(BUF, NH, BREG) { const char* q_ = lds + (BUF) * 65536 + boff + (NH) * 4096; \
    _Pragma("unroll") for (int nf = 0; nf < 2; ++nf) {                                  \
      BREG[nf][0] = *(const f16x8*)(q_ + nf * 2048);                                    \
      BREG[nf][1] = *(const f16x8*)((const char*)((size_t)(q_ + nf * 2048) ^ 64)); } }
#define MM(MH, NH, BREG) { __builtin_amdgcn_s_setprio(1);                               \
    _Pragma("unroll") for (int mf = 0; mf < 4; ++mf)                                    \
      _Pragma("unroll") for (int nf = 0; nf < 2; ++nf)                                  \
        _Pragma("unroll") for (int kk = 0; kk < 2; ++kk)                                \
          acc[(MH)*4+mf][(NH)*2+nf] = MFMA16(a[mf][kk], BREG[nf][kk],                   \
                                             acc[(MH)*4+mf][(NH)*2+nf]);                \
    __builtin_amdgcn_s_setprio(0); }
#define VM6 asm volatile("s_waitcnt vmcnt(6)" ::: "memory")
#define VM0 asm volatile("s_waitcnt vmcnt(0)" ::: "memory")
#define BAR __builtin_amdgcn_s_barrier()

  const int nT = K >> 6;  // 16 for K=1024 (even, >= 4)

  // ---- prologue: tile0 (8) + tile1 partial (A{0,128}, B all) = 14 in flight
  STG_A(0, 0); STG_A(0, 64); STG_A(0, 128); STG_A(0, 192);
  STG_B(0, 0); STG_B(0, 64); STG_B(0, 128); STG_B(0, 192);
  STG_A(1, 0); STG_A(1, 128);
  STG_B(1, 0); STG_B(1, 64); STG_B(1, 128); STG_B(1, 192);
  asm volatile("s_waitcnt vmcnt(6)" ::: "memory");  // retire tile0's 8
  BAR;

  const int nPair = (nT - 2) >> 1;  // main tiles 0..nT-3, two per iteration
  for (int i = 0; i < nPair; ++i) {
    const int t0 = 2 * i;
    // ---- tile t0 (buf0)
    RD_B(0, 0, b0); RD_A(0, 0); STG_A(t0 + 1, 64); STG_A(t0 + 1, 192); BAR; MM(0, 0, b0); BAR;
    RD_B(0, 1, b1); STG_A(t0 + 2, 0); STG_A(t0 + 2, 128); BAR; MM(0, 1, b1); BAR;
    RD_A(0, 1); STG_B(t0 + 2, 0); STG_B(t0 + 2, 64); BAR; MM(1, 1, b1); BAR;
    STG_B(t0 + 2, 128); STG_B(t0 + 2, 192); VM6; BAR; MM(1, 0, b0); BAR;
    // ---- tile t0+1 (buf1)
    RD_B(1, 0, b0); RD_A(1, 0); STG_A(t0 + 2, 64); STG_A(t0 + 2, 192); BAR; MM(0, 0, b0); BAR;
    RD_B(1, 1, b1); STG_A(t0 + 3, 0); STG_A(t0 + 3, 128); BAR; MM(0, 1, b1); BAR;
    RD_A(1, 1); STG_B(t0 + 3, 0); STG_B(t0 + 3, 64); BAR; MM(1, 1, b1); BAR;
    STG_B(t0 + 3, 128); STG_B(t0 + 3, 192); VM6; BAR; MM(1, 0, b0); BAR;
  }
  // ---- epilogue: tile nT-2 (buf0) — finish staging tile nT-1, drain to 0
  RD_B(0, 0, b0); RD_A(0, 0); STG_A(nT - 1, 64); STG_A(nT - 1, 192); BAR; MM(0, 0, b0); BAR;
  RD_B(0, 1, b1); BAR; MM(0, 1, b1); BAR;
  RD_A(0, 1); BAR; MM(1, 1, b1); BAR;
  VM0; BAR; MM(1, 0, b0); BAR;
  // ---- tile nT-1 (buf1)
  RD_B(1, 0, b0); RD_A(1, 0); BAR; MM(0, 0, b0); BAR;
  RD_B(1, 1, b1); BAR; MM(0, 1, b1); BAR;
  RD_A(1, 1); BAR; MM(1, 1, b1); BAR;
  MM(1, 0, b0);

  // ---- C write: 16x16 C-layout col = l15, row = lhi*4 + reg (verified m89)
  const long rbase = (long)tm * 256 + wr * 128;
  const int cbase = tn * 256 + wc * 64;
#pragma unroll
  for (int mf = 0; mf < 8; ++mf)
#pragma unroll
    for (int nf = 0; nf < 4; ++nf) {
      int c = cbase + nf * 16 + l15;
      float bv = FINAL ? bias[c] : 0.f;
#pragma unroll
      for (int j = 0; j < 4; ++j) {
        long r = rbase + mf * 16 + lhi * 4 + j;
        float v = acc[mf][nf][j];
        if (FINAL) ((float*)Cout)[r * N + c] = v + bv;
        else ((_Float16*)Cout)[r * N + c] = (_Float16)v;
      }
    }
#undef STG_A
#undef STG_B
#undef RD_A
#undef RD_B
#undef MM
#undef VM6
#undef VM0
#undef BAR
}

extern "C" void kernel_launch(void* const* d_in, const int* in_sizes, int n_in,
                              void* d_out, int out_size, void* d_ws, size_t ws_size,
                              hipStream_t stream) {
  const float* x   = (const float*)d_in[0];
  const float* ctx = (const float*)d_in[1];
  const float* Wq  = (const float*)d_in[2];
  const float* Wk  = (const float*)d_in[3];
  const float* Wv  = (const float*)d_in[4];
  const float* Wo  = (const float*)d_in[5];
  const float* bo  = (const float*)d_in[6];

  char* ws = (char*)d_ws;
  _Float16* xh   = (_Float16*)(ws + 0);           // [32768][1024] x-f16; later attnOut
  _Float16* Wqt  = (_Float16*)(ws + 67108864);    // [1024][1024]
  _Float16* Wkt  = (_Float16*)(ws + 69206016);    // [1024][768]
  _Float16* Wvt  = (_Float16*)(ws + 70778880);    // [1024][768]
  _Float16* Wot  = (_Float16*)(ws + 72351744);    // [1024][1024]
  _Float16* ctxh = (_Float16*)(ws + 74448896);    // [616][768]
  _Float16* Kg   = (_Float16*)(ws + 75395072);    // [128][77][64]
  _Float16* Vtg  = (_Float16*)(ws + 76656640);    // [128][64][128]
  _Float16* Qh   = (_Float16*)d_out;              // [32768][1024] f16 scratch in d_out

  k_cvt16<<<4096, 256, 0, stream>>>(x, xh, 33554432 / 8);
  k_cvt16<<<231, 256, 0, stream>>>(ctx, ctxh, 473088 / 8);
  k_transpose<<<dim3(16, 16), 256, 0, stream>>>(Wq, Wqt, 1024, 1024);
  k_transpose<<<dim3(16, 12), 256, 0, stream>>>(Wk, Wkt, 768, 1024);
  k_transpose<<<dim3(16, 12), 256, 0, stream>>>(Wv, Wvt, 768, 1024);
  k_transpose<<<dim3(16, 16), 256, 0, stream>>>(Wo, Wot, 1024, 1024);
  hipMemsetAsync(Vtg, 0, 2097152, stream);
  k_kvproj<<<dim3(39, 64), 64, 0, stream>>>(ctxh, Wkt, Wvt, Kg, Vtg);
  // GEMM1: Q projection -> d_out (f16 scratch); grid 512 (%8==0 for T1)
  k_gemm5<0><<<dim3(512), dim3(512), 0, stream>>>(xh, Wqt, (void*)Qh, nullptr, 32768, 1024, 1024);
  // attention: reads Qh (d_out), writes attnOut -> xh
  k_attn<<<dim3(64, 128), 256, 0, stream>>>(Qh, Kg, Vtg, xh);
  // GEMM2: O projection + bias -> d_out (f32)
  k_gemm5<1><<<dim3(512), dim3(512), 0, stream>>>(xh, Wot, d_out, bo, 32768, 1024, 1024);
}

// Round 8
// 289.732 us; speedup vs baseline: 1.4462x; 1.4462x over previous
//
#include <hip/hip_runtime.h>
#include <hip/hip_bf16.h>

typedef _Float16 f16x8 __attribute__((ext_vector_type(8)));
typedef float f32x4 __attribute__((ext_vector_type(4)));

#define MFMA16(a, b, c) __builtin_amdgcn_mfma_f32_16x16x32_f16(a, b, c, 0, 0, 0)

__device__ __forceinline__ void load_lds16(const void* g, void* l) {
  __builtin_amdgcn_global_load_lds(
      (__attribute__((address_space(1))) void*)g,
      (__attribute__((address_space(3))) void*)l, 16, 0, 0);
}

// ---------------- f32 -> f16 convert (8 elems / thread / iter) ----------------
__global__ __launch_bounds__(256) void k_cvt16(const float* __restrict__ in,
                                               _Float16* __restrict__ out, int n8) {
  int stride = gridDim.x * blockDim.x;
  for (int i = blockIdx.x * blockDim.x + threadIdx.x; i < n8; i += stride) {
    const float4* p = (const float4*)(in + (size_t)i * 8);
    float4 a = p[0], b = p[1];
    f16x8 v = {(_Float16)a.x, (_Float16)a.y, (_Float16)a.z, (_Float16)a.w,
               (_Float16)b.x, (_Float16)b.y, (_Float16)b.z, (_Float16)b.w};
    *(f16x8*)(out + (size_t)i * 8) = v;
  }
}

// ---------- transpose + convert: in[K][N] f32 -> out[N][K] f16, 64x64 tiles ----------
__global__ __launch_bounds__(256) void k_transpose(const float* __restrict__ in,
                                                   _Float16* __restrict__ out, int K, int N) {
  __shared__ float tile[64][65];
  int k0 = blockIdx.y * 64, n0 = blockIdx.x * 64;
  int t = threadIdx.x;
  {
    int nn = t & 63, kb = t >> 6;
#pragma unroll
    for (int i = 0; i < 16; ++i) {
      int kk = kb + i * 4;
      tile[kk][nn] = in[(size_t)(k0 + kk) * N + n0 + nn];
    }
  }
  __syncthreads();
  {
    int kk = t & 63, nb = t >> 6;
#pragma unroll
    for (int i = 0; i < 16; ++i) {
      int nn = nb + i * 4;
      out[(size_t)(n0 + nn) * K + k0 + kk] = (_Float16)tile[kk][nn];
    }
  }
}

// ---------------- K/V projection: ctxh[616][768] @ W^T -> heads ----------------
__global__ __launch_bounds__(64) void k_kvproj(const _Float16* __restrict__ ctxh,
                                               const _Float16* __restrict__ Wkt,
                                               const _Float16* __restrict__ Wvt,
                                               _Float16* __restrict__ Kg,
                                               _Float16* __restrict__ Vtg) {
  int mt = blockIdx.x, nt = blockIdx.y;
  int lane = threadIdx.x;
  int l15 = lane & 15, lhi = lane >> 4;
  int arow = mt * 16 + l15;
  if (arow > 615) arow = 615;  // clamp; masked at write
  const _Float16* ap = ctxh + (size_t)arow * 768 + lhi * 8;
  const _Float16* kp = Wkt + (size_t)(nt * 16 + l15) * 768 + lhi * 8;
  const _Float16* vp = Wvt + (size_t)(nt * 16 + l15) * 768 + lhi * 8;
  f32x4 ak = {0.f, 0.f, 0.f, 0.f}, av = {0.f, 0.f, 0.f, 0.f};
#pragma unroll 4
  for (int ks = 0; ks < 24; ++ks) {
    f16x8 a = *(const f16x8*)(ap + ks * 32);
    f16x8 bk = *(const f16x8*)(kp + ks * 32);
    f16x8 bv = *(const f16x8*)(vp + ks * 32);
    ak = MFMA16(a, bk, ak);
    av = MFMA16(a, bv, av);
  }
  int n = nt * 16 + l15, h = n >> 6, d = n & 63;
#pragma unroll
  for (int j = 0; j < 4; ++j) {
    int gm = mt * 16 + lhi * 4 + j;
    if (gm < 616) {
      int b = gm / 77, m = gm - b * 77;
      Kg[((size_t)(b * 16 + h) * 77 + m) * 64 + d] = (_Float16)ak[j];
      Vtg[((size_t)(b * 16 + h) * 64 + d) * 128 + m] = (_Float16)av[j];
    }
  }
}

// ---------------- attention: one block = one (b,h) x 64 query rows ----------------
__global__ __launch_bounds__(256) void k_attn(const _Float16* __restrict__ Qh,
                                              const _Float16* __restrict__ Kg,
                                              const _Float16* __restrict__ Vtg,
                                              _Float16* __restrict__ Out) {
  __shared__ __align__(16) char Kl[80 * 128];
  __shared__ __align__(16) char Vl[64 * 256];
  __shared__ __align__(16) char Pl[4 * 16 * 256];
  int bh = blockIdx.y, b = bh >> 4, h = bh & 15;
  int t = threadIdx.x, wid = t >> 6, lane = t & 63;
  int l15 = lane & 15, lhi = lane >> 4;

  const _Float16* Kgp = Kg + (size_t)bh * (77 * 64);
  const _Float16* Vgp = Vtg + (size_t)bh * (64 * 128);

  for (int idx = t; idx < 640; idx += 256) {
    int m = idx >> 3, c = (idx & 7) * 8;
    f16x8 v = {};
    if (m < 77) v = *(const f16x8*)(Kgp + m * 64 + c);
    *(f16x8*)(Kl + ((m * 128 + c * 2) ^ ((m & 7) << 4))) = v;
  }
  for (int idx = t; idx < 1024; idx += 256) {
    int d = idx >> 4, c = (idx & 15) * 8;
    f16x8 v = *(const f16x8*)(Vgp + d * 128 + c);
    *(f16x8*)(Vl + ((d * 256 + c * 2) ^ ((d & 7) << 4))) = v;
  }
  char* myP = Pl + wid * 4096;
#pragma unroll
  for (int i = 0; i < 4; ++i) *(f16x8*)(myP + lane * 64 + i * 16) = f16x8{};
  __syncthreads();

  int qrow = b * 4096 + blockIdx.x * 64 + wid * 16 + l15;
  const _Float16* qp = Qh + (size_t)qrow * 1024 + h * 64 + lhi * 8;
  f16x8 q0 = *(const f16x8*)qp;
  f16x8 q1 = *(const f16x8*)(qp + 32);

  float e[5][4];
  float mx[4] = {-1e30f, -1e30f, -1e30f, -1e30f};
#pragma unroll
  for (int ct = 0; ct < 5; ++ct) {
    int m = ct * 16 + l15;
    int d0b = lhi * 16;
    f16x8 k0 = *(const f16x8*)(Kl + ((m * 128 + d0b) ^ ((m & 7) << 4)));
    f16x8 k1 = *(const f16x8*)(Kl + ((m * 128 + 64 + d0b) ^ ((m & 7) << 4)));
    f32x4 acc = {0.f, 0.f, 0.f, 0.f};
    acc = MFMA16(q0, k0, acc);
    acc = MFMA16(q1, k1, acc);
    bool valid = m < 77;
#pragma unroll
    for (int j = 0; j < 4; ++j) {
      float v = valid ? acc[j] * 0.125f : -1e30f;
      e[ct][j] = v;
      mx[j] = fmaxf(mx[j], v);
    }
  }
#pragma unroll
  for (int off = 1; off < 16; off <<= 1)
#pragma unroll
    for (int j = 0; j < 4; ++j) mx[j] = fmaxf(mx[j], __shfl_xor(mx[j], off, 64));
  float sm[4] = {0.f, 0.f, 0.f, 0.f};
#pragma unroll
  for (int ct = 0; ct < 5; ++ct)
#pragma unroll
    for (int j = 0; j < 4; ++j) {
      float ev = __expf(e[ct][j] - mx[j]);
      e[ct][j] = ev;
      sm[j] += ev;
    }
#pragma unroll
  for (int off = 1; off < 16; off <<= 1)
#pragma unroll
    for (int j = 0; j < 4; ++j) sm[j] += __shfl_xor(sm[j], off, 64);
  float rs[4];
#pragma unroll
  for (int j = 0; j < 4; ++j) rs[j] = 1.0f / sm[j];

#pragma unroll
  for (int ct = 0; ct < 5; ++ct) {
    int m = ct * 16 + l15;
#pragma unroll
    for (int j = 0; j < 4; ++j) {
      int r = lhi * 4 + j;
      *(_Float16*)(myP + ((r * 256 + m * 2) ^ ((r & 7) << 4))) =
          (_Float16)(e[ct][j] * rs[j]);
    }
  }

  f32x4 o[4] = {{0.f,0.f,0.f,0.f},{0.f,0.f,0.f,0.f},{0.f,0.f,0.f,0.f},{0.f,0.f,0.f,0.f}};
#pragma unroll
  for (int ks = 0; ks < 3; ++ks) {
    int m0b = ks * 64 + lhi * 16;
    f16x8 pa = *(const f16x8*)(myP + ((l15 * 256 + m0b) ^ ((l15 & 7) << 4)));
#pragma unroll
    for (int dt = 0; dt < 4; ++dt) {
      int d = dt * 16 + l15;
      f16x8 vb = *(const f16x8*)(Vl + ((d * 256 + m0b) ^ ((d & 7) << 4)));
      o[dt] = MFMA16(pa, vb, o[dt]);
    }
  }
  _Float16* op = Out + (size_t)(b * 4096 + blockIdx.x * 64 + wid * 16) * 1024 + h * 64;
#pragma unroll
  for (int dt = 0; dt < 4; ++dt)
#pragma unroll
    for (int j = 0; j < 4; ++j) {
      int r = lhi * 4 + j;
      op[(size_t)r * 1024 + dt * 16 + l15] = (_Float16)o[dt][j];
    }
}

// ====== 256x256 GEMM, 8-phase (R5 structure) + full row&7 swizzle, INT offsets ======
// A [M][K] f16, Bt [N][K] f16. BK=64 (8 x 16B chunks/row), 512 thr = 8 waves (2Mx4N),
// per-wave C = 128x64 = 8 m-frags x 4 n-frags of 16x16. 4 phases/K-tile, 16 MFMA each.
// Swizzle: chunk c of row r stored at c ^ (r&7) (conflict-free, R6/R7: CONFLICT==0).
// Staging pre-swizzles the GLOBAL source chunk (linear LDS dest); reads apply the
// same XOR **computed as integer offsets cs0/cs1 into the __shared__ array** — no
// pointer/size_t bit-ops (R7 lesson: size_t^64 pointer XOR defeats LDS addrspace
// inference/offset folding and serialized the pipeline, 86.6 -> 149 us).
template <int FINAL>
__global__ __launch_bounds__(512, 2) void k_gemm6(const _Float16* __restrict__ A,
                                                  const _Float16* __restrict__ Bt,
                                                  void* __restrict__ Cout,
                                                  const float* __restrict__ bias,
                                                  int M, int N, int K) {
  __shared__ __align__(16) char lds[131072];
  const int t = threadIdx.x, wid = t >> 6, lane = t & 63;
  const int wr = wid >> 2, wc = wid & 3;  // 2M x 4N wave grid
  const int l15 = lane & 15, lhi = lane >> 4;

  // T1: bijective XCD swizzle (nwg % 8 == 0)
  int nwg = gridDim.x, bid = blockIdx.x;
  int wg = ((nwg & 7) == 0) ? ((bid & 7) * (nwg >> 3) + (bid >> 3)) : bid;
  const int nTN = N >> 8;
  const int tm = wg / nTN, tn = wg % nTN;

  const _Float16* Ag = A + (size_t)tm * 256 * K;
  const _Float16* Bg = Bt + (size_t)tn * 256 * K;
  // staging source: row = wid*8 + (lane>>3) (+slice; slices = 0 mod 8), source
  // chunk = destchunk ^ (row&7) = (lane&7) ^ ((lane>>3)&7)   [R6/R7-verified]
  const size_t stg = (size_t)(wid * 8 + (lane >> 3)) * K +
                     (size_t)(((lane & 7) ^ ((lane >> 3) & 7)) * 8);
  const int dstg = wid * 1024;  // linear wave dest (HW adds lane*16)

  // read swizzle as int offsets: chunk(kk) = (kk*4 + lhi) ^ (l15&7)
  const int x7 = l15 & 7;
  const int cs0 = (lhi ^ x7) << 4;        // kk = 0
  const int cs1 = ((4 + lhi) ^ x7) << 4;  // kk = 1
  const int aoff = wr * 16384 + l15 * 128;         // + mh*8192 + mf*2048 + cs{kk}
  const int boff = 32768 + wc * 8192 + l15 * 128;  // + nh*4096 + nf*2048 + cs{kk}

  f32x4 acc[8][4];
#pragma unroll
  for (int i = 0; i < 8; ++i)
#pragma unroll
    for (int j = 0; j < 4; ++j) acc[i][j] = f32x4{0.f, 0.f, 0.f, 0.f};
  f16x8 a[4][2], b0[2][2], b1[2][2];

#define STG_A(T, RB) load_lds16(Ag + stg + (size_t)(RB) * K + (T) * 64, \
                                lds + ((T) & 1) * 65536 + (RB) * 128 + dstg)
#define STG_B(T, RB) load_lds16(Bg + stg + (size_t)(RB) * K + (T) * 64, \
                                lds + ((T) & 1) * 65536 + 32768 + (RB) * 128 + dstg)
#define RD_A(BUF, MH) { const int p_ = (BUF) * 65536 + aoff + (MH) * 8192;              \
    _Pragma("unroll") for (int mf = 0; mf < 4; ++mf) {                                  \
      a[mf][0] = *(const f16x8*)&lds[p_ + mf * 2048 + cs0];                             \
      a[mf][1] = *(const f16x8*)&lds[p_ + mf * 2048 + cs1]; } }
#define RD_B(BUF, NH, BREG) { const int q_ = (BUF) * 65536 + boff + (NH) * 4096;        \
    _Pragma("unroll") for (int nf = 0; nf < 2; ++nf) {                                  \
      BREG[nf][0] = *(const f16x8*)&lds[q_ + nf * 2048 + cs0];                          \
      BREG[nf][1] = *(const f16x8*)&lds[q_ + nf * 2048 + cs1]; } }
#define MM(MH, NH, BREG) { __builtin_amdgcn_s_setprio(1);                               \
    _Pragma("unroll") for (int mf = 0; mf < 4; ++mf)                                    \
      _Pragma("unroll") for (int nf = 0; nf < 2; ++nf)                                  \
        _Pragma("unroll") for (int kk = 0; kk < 2; ++kk)                                \
          acc[(MH)*4+mf][(NH)*2+nf] = MFMA16(a[mf][kk], BREG[nf][kk],                   \
                                             acc[(MH)*4+mf][(NH)*2+nf]);                \
    __builtin_amdgcn_s_setprio(0); }
#define VM6 asm volatile("s_waitcnt vmcnt(6)" ::: "memory")
#define VM0 asm volatile("s_waitcnt vmcnt(0)" ::: "memory")
#define BAR __builtin_amdgcn_s_barrier()

  const int nT = K >> 6;  // 16 for K=1024 (even, >= 4)

  // ---- prologue: tile0 (8) + tile1 partial (A{0,128}, B all) = 14 in flight
  STG_A(0, 0); STG_A(0, 64); STG_A(0, 128); STG_A(0, 192);
  STG_B(0, 0); STG_B(0, 64); STG_B(0, 128); STG_B(0, 192);
  STG_A(1, 0); STG_A(1, 128);
  STG_B(1, 0); STG_B(1, 64); STG_B(1, 128); STG_B(1, 192);
  asm volatile("s_waitcnt vmcnt(6)" ::: "memory");  // retire tile0's 8
  BAR;

  const int nPair = (nT - 2) >> 1;  // main tiles 0..nT-3, two per iteration
  for (int i = 0; i < nPair; ++i) {
    const int t0 = 2 * i;
    // ---- tile t0 (buf0)
    RD_B(0, 0, b0); RD_A(0, 0); STG_A(t0 + 1, 64); STG_A(t0 + 1, 192); BAR; MM(0, 0, b0); BAR;
    RD_B(0, 1, b1); STG_A(t0 + 2, 0); STG_A(t0 + 2, 128); BAR; MM(0, 1, b1); BAR;
    RD_A(0, 1); STG_B(t0 + 2, 0); STG_B(t0 + 2, 64); BAR; MM(1, 1, b1); BAR;
    STG_B(t0 + 2, 128); STG_B(t0 + 2, 192); VM6; BAR; MM(1, 0, b0); BAR;
    // ---- tile t0+1 (buf1)
    RD_B(1, 0, b0); RD_A(1, 0); STG_A(t0 + 2, 64); STG_A(t0 + 2, 192); BAR; MM(0, 0, b0); BAR;
    RD_B(1, 1, b1); STG_A(t0 + 3, 0); STG_A(t0 + 3, 128); BAR; MM(0, 1, b1); BAR;
    RD_A(1, 1); STG_B(t0 + 3, 0); STG_B(t0 + 3, 64); BAR; MM(1, 1, b1); BAR;
    STG_B(t0 + 3, 128); STG_B(t0 + 3, 192); VM6; BAR; MM(1, 0, b0); BAR;
  }
  // ---- epilogue: tile nT-2 (buf0) — finish staging tile nT-1, drain to 0
  RD_B(0, 0, b0); RD_A(0, 0); STG_A(nT - 1, 64); STG_A(nT - 1, 192); BAR; MM(0, 0, b0); BAR;
  RD_B(0, 1, b1); BAR; MM(0, 1, b1); BAR;
  RD_A(0, 1); BAR; MM(1, 1, b1); BAR;
  VM0; BAR; MM(1, 0, b0); BAR;
  // ---- tile nT-1 (buf1)
  RD_B(1, 0, b0); RD_A(1, 0); BAR; MM(0, 0, b0); BAR;
  RD_B(1, 1, b1); BAR; MM(0, 1, b1); BAR;
  RD_A(1, 1); BAR; MM(1, 1, b1); BAR;
  MM(1, 0, b0);

  // ---- C write: 16x16 C-layout col = l15, row = lhi*4 + reg (verified m89)
  const long rbase = (long)tm * 256 + wr * 128;
  const int cbase = tn * 256 + wc * 64;
#pragma unroll
  for (int mf = 0; mf < 8; ++mf)
#pragma unroll
    for (int nf = 0; nf < 4; ++nf) {
      int c = cbase + nf * 16 + l15;
      float bv = FINAL ? bias[c] : 0.f;
#pragma unroll
      for (int j = 0; j < 4; ++j) {
        long r = rbase + mf * 16 + lhi * 4 + j;
        float v = acc[mf][nf][j];
        if (FINAL) ((float*)Cout)[r * N + c] = v + bv;
        else ((_Float16*)Cout)[r * N + c] = (_Float16)v;
      }
    }
#undef STG_A
#undef STG_B
#undef RD_A
#undef RD_B
#undef MM
#undef VM6
#undef VM0
#undef BAR
}

extern "C" void kernel_launch(void* const* d_in, const int* in_sizes, int n_in,
                              void* d_out, int out_size, void* d_ws, size_t ws_size,
                              hipStream_t stream) {
  const float* x   = (const float*)d_in[0];
  const float* ctx = (const float*)d_in[1];
  const float* Wq  = (const float*)d_in[2];
  const float* Wk  = (const float*)d_in[3];
  const float* Wv  = (const float*)d_in[4];
  const float* Wo  = (const float*)d_in[5];
  const float* bo  = (const float*)d_in[6];

  char* ws = (char*)d_ws;
  _Float16* xh   = (_Float16*)(ws + 0);           // [32768][1024] x-f16; later attnOut
  _Float16* Wqt  = (_Float16*)(ws + 67108864);    // [1024][1024]
  _Float16* Wkt  = (_Float16*)(ws + 69206016);    // [1024][768]
  _Float16* Wvt  = (_Float16*)(ws + 70778880);    // [1024][768]
  _Float16* Wot  = (_Float16*)(ws + 72351744);    // [1024][1024]
  _Float16* ctxh = (_Float16*)(ws + 74448896);    // [616][768]
  _Float16* Kg   = (_Float16*)(ws + 75395072);    // [128][77][64]
  _Float16* Vtg  = (_Float16*)(ws + 76656640);    // [128][64][128]
  _Float16* Qh   = (_Float16*)d_out;              // [32768][1024] f16 scratch in d_out

  k_cvt16<<<4096, 256, 0, stream>>>(x, xh, 33554432 / 8);
  k_cvt16<<<231, 256, 0, stream>>>(ctx, ctxh, 473088 / 8);
  k_transpose<<<dim3(16, 16), 256, 0, stream>>>(Wq, Wqt, 1024, 1024);
  k_transpose<<<dim3(16, 12), 256, 0, stream>>>(Wk, Wkt, 768, 1024);
  k_transpose<<<dim3(16, 12), 256, 0, stream>>>(Wv, Wvt, 768, 1024);
  k_transpose<<<dim3(16, 16), 256, 0, stream>>>(Wo, Wot, 1024, 1024);
  hipMemsetAsync(Vtg, 0, 2097152, stream);
  k_kvproj<<<dim3(39, 64), 64, 0, stream>>>(ctxh, Wkt, Wvt, Kg, Vtg);
  // GEMM1: Q projection -> d_out (f16 scratch); grid 512 (%8==0 for T1)
  k_gemm6<0><<<dim3(512), dim3(512), 0, stream>>>(xh, Wqt, (void*)Qh, nullptr, 32768, 1024, 1024);
  // attention: reads Qh (d_out), writes attnOut -> xh
  k_attn<<<dim3(64, 128), 256, 0, stream>>>(Qh, Kg, Vtg, xh);
  // GEMM2: O projection + bias -> d_out (f32)
  k_gemm6<1><<<dim3(512), dim3(512), 0, stream>>>(xh, Wot, d_out, bo, 32768, 1024, 1024);
}

// Round 9
// 284.561 us; speedup vs baseline: 1.4725x; 1.0182x over previous
//
#include <hip/hip_runtime.h>
#include <hip/hip_bf16.h>

typedef _Float16 f16x8 __attribute__((ext_vector_type(8)));
typedef float f32x4 __attribute__((ext_vector_type(4)));

#define MFMA16(a, b, c) __builtin_amdgcn_mfma_f32_16x16x32_f16(a, b, c, 0, 0, 0)

__device__ __forceinline__ void load_lds16(const void* g, void* l) {
  __builtin_amdgcn_global_load_lds(
      (__attribute__((address_space(1))) void*)g,
      (__attribute__((address_space(3))) void*)l, 16, 0, 0);
}

// ---------------- f32 -> f16 convert (8 elems / thread / iter) ----------------
__global__ __launch_bounds__(256) void k_cvt16(const float* __restrict__ in,
                                               _Float16* __restrict__ out, int n8) {
  int stride = gridDim.x * blockDim.x;
  for (int i = blockIdx.x * blockDim.x + threadIdx.x; i < n8; i += stride) {
    const float4* p = (const float4*)(in + (size_t)i * 8);
    float4 a = p[0], b = p[1];
    f16x8 v = {(_Float16)a.x, (_Float16)a.y, (_Float16)a.z, (_Float16)a.w,
               (_Float16)b.x, (_Float16)b.y, (_Float16)b.z, (_Float16)b.w};
    *(f16x8*)(out + (size_t)i * 8) = v;
  }
}

// ---------- transpose + convert: in[K][N] f32 -> out[N][K] f16, 64x64 tiles ----------
__global__ __launch_bounds__(256) void k_transpose(const float* __restrict__ in,
                                                   _Float16* __restrict__ out, int K, int N) {
  __shared__ float tile[64][65];
  int k0 = blockIdx.y * 64, n0 = blockIdx.x * 64;
  int t = threadIdx.x;
  {
    int nn = t & 63, kb = t >> 6;
#pragma unroll
    for (int i = 0; i < 16; ++i) {
      int kk = kb + i * 4;
      tile[kk][nn] = in[(size_t)(k0 + kk) * N + n0 + nn];
    }
  }
  __syncthreads();
  {
    int kk = t & 63, nb = t >> 6;
#pragma unroll
    for (int i = 0; i < 16; ++i) {
      int nn = nb + i * 4;
      out[(size_t)(n0 + nn) * K + k0 + kk] = (_Float16)tile[kk][nn];
    }
  }
}

// ---------------- K/V projection: ctxh[616][768] @ W^T -> heads ----------------
__global__ __launch_bounds__(64) void k_kvproj(const _Float16* __restrict__ ctxh,
                                               const _Float16* __restrict__ Wkt,
                                               const _Float16* __restrict__ Wvt,
                                               _Float16* __restrict__ Kg,
                                               _Float16* __restrict__ Vtg) {
  int mt = blockIdx.x, nt = blockIdx.y;
  int lane = threadIdx.x;
  int l15 = lane & 15, lhi = lane >> 4;
  int arow = mt * 16 + l15;
  if (arow > 615) arow = 615;  // clamp; masked at write
  const _Float16* ap = ctxh + (size_t)arow * 768 + lhi * 8;
  const _Float16* kp = Wkt + (size_t)(nt * 16 + l15) * 768 + lhi * 8;
  const _Float16* vp = Wvt + (size_t)(nt * 16 + l15) * 768 + lhi * 8;
  f32x4 ak = {0.f, 0.f, 0.f, 0.f}, av = {0.f, 0.f, 0.f, 0.f};
#pragma unroll 4
  for (int ks = 0; ks < 24; ++ks) {
    f16x8 a = *(const f16x8*)(ap + ks * 32);
    f16x8 bk = *(const f16x8*)(kp + ks * 32);
    f16x8 bv = *(const f16x8*)(vp + ks * 32);
    ak = MFMA16(a, bk, ak);
    av = MFMA16(a, bv, av);
  }
  int n = nt * 16 + l15, h = n >> 6, d = n & 63;
#pragma unroll
  for (int j = 0; j < 4; ++j) {
    int gm = mt * 16 + lhi * 4 + j;
    if (gm < 616) {
      int b = gm / 77, m = gm - b * 77;
      Kg[((size_t)(b * 16 + h) * 77 + m) * 64 + d] = (_Float16)ak[j];
      Vtg[((size_t)(b * 16 + h) * 64 + d) * 128 + m] = (_Float16)av[j];
    }
  }
}

// ---------------- attention: one block = one (b,h) x 64 query rows ----------------
__global__ __launch_bounds__(256) void k_attn(const _Float16* __restrict__ Qh,
                                              const _Float16* __restrict__ Kg,
                                              const _Float16* __restrict__ Vtg,
                                              _Float16* __restrict__ Out) {
  __shared__ __align__(16) char Kl[80 * 128];
  __shared__ __align__(16) char Vl[64 * 256];
  __shared__ __align__(16) char Pl[4 * 16 * 256];
  int bh = blockIdx.y, b = bh >> 4, h = bh & 15;
  int t = threadIdx.x, wid = t >> 6, lane = t & 63;
  int l15 = lane & 15, lhi = lane >> 4;

  const _Float16* Kgp = Kg + (size_t)bh * (77 * 64);
  const _Float16* Vgp = Vtg + (size_t)bh * (64 * 128);

  for (int idx = t; idx < 640; idx += 256) {
    int m = idx >> 3, c = (idx & 7) * 8;
    f16x8 v = {};
    if (m < 77) v = *(const f16x8*)(Kgp + m * 64 + c);
    *(f16x8*)(Kl + ((m * 128 + c * 2) ^ ((m & 7) << 4))) = v;
  }
  for (int idx = t; idx < 1024; idx += 256) {
    int d = idx >> 4, c = (idx & 15) * 8;
    f16x8 v = *(const f16x8*)(Vgp + d * 128 + c);
    *(f16x8*)(Vl + ((d * 256 + c * 2) ^ ((d & 7) << 4))) = v;
  }
  char* myP = Pl + wid * 4096;
#pragma unroll
  for (int i = 0; i < 4; ++i) *(f16x8*)(myP + lane * 64 + i * 16) = f16x8{};
  __syncthreads();

  int qrow = b * 4096 + blockIdx.x * 64 + wid * 16 + l15;
  const _Float16* qp = Qh + (size_t)qrow * 1024 + h * 64 + lhi * 8;
  f16x8 q0 = *(const f16x8*)qp;
  f16x8 q1 = *(const f16x8*)(qp + 32);

  float e[5][4];
  float mx[4] = {-1e30f, -1e30f, -1e30f, -1e30f};
#pragma unroll
  for (int ct = 0; ct < 5; ++ct) {
    int m = ct * 16 + l15;
    int d0b = lhi * 16;
    f16x8 k0 = *(const f16x8*)(Kl + ((m * 128 + d0b) ^ ((m & 7) << 4)));
    f16x8 k1 = *(const f16x8*)(Kl + ((m * 128 + 64 + d0b) ^ ((m & 7) << 4)));
    f32x4 acc = {0.f, 0.f, 0.f, 0.f};
    acc = MFMA16(q0, k0, acc);
    acc = MFMA16(q1, k1, acc);
    bool valid = m < 77;
#pragma unroll
    for (int j = 0; j < 4; ++j) {
      float v = valid ? acc[j] * 0.125f : -1e30f;
      e[ct][j] = v;
      mx[j] = fmaxf(mx[j], v);
    }
  }
#pragma unroll
  for (int off = 1; off < 16; off <<= 1)
#pragma unroll
    for (int j = 0; j < 4; ++j) mx[j] = fmaxf(mx[j], __shfl_xor(mx[j], off, 64));
  float sm[4] = {0.f, 0.f, 0.f, 0.f};
#pragma unroll
  for (int ct = 0; ct < 5; ++ct)
#pragma unroll
    for (int j = 0; j < 4; ++j) {
      float ev = __expf(e[ct][j] - mx[j]);
      e[ct][j] = ev;
      sm[j] += ev;
    }
#pragma unroll
  for (int off = 1; off < 16; off <<= 1)
#pragma unroll
    for (int j = 0; j < 4; ++j) sm[j] += __shfl_xor(sm[j], off, 64);
  float rs[4];
#pragma unroll
  for (int j = 0; j < 4; ++j) rs[j] = 1.0f / sm[j];

#pragma unroll
  for (int ct = 0; ct < 5; ++ct) {
    int m = ct * 16 + l15;
#pragma unroll
    for (int j = 0; j < 4; ++j) {
      int r = lhi * 4 + j;
      *(_Float16*)(myP + ((r * 256 + m * 2) ^ ((r & 7) << 4))) =
          (_Float16)(e[ct][j] * rs[j]);
    }
  }

  f32x4 o[4] = {{0.f,0.f,0.f,0.f},{0.f,0.f,0.f,0.f},{0.f,0.f,0.f,0.f},{0.f,0.f,0.f,0.f}};
#pragma unroll
  for (int ks = 0; ks < 3; ++ks) {
    int m0b = ks * 64 + lhi * 16;
    f16x8 pa = *(const f16x8*)(myP + ((l15 * 256 + m0b) ^ ((l15 & 7) << 4)));
#pragma unroll
    for (int dt = 0; dt < 4; ++dt) {
      int d = dt * 16 + l15;
      f16x8 vb = *(const f16x8*)(Vl + ((d * 256 + m0b) ^ ((d & 7) << 4)));
      o[dt] = MFMA16(pa, vb, o[dt]);
    }
  }
  _Float16* op = Out + (size_t)(b * 4096 + blockIdx.x * 64 + wid * 16) * 1024 + h * 64;
#pragma unroll
  for (int dt = 0; dt < 4; ++dt)
#pragma unroll
    for (int j = 0; j < 4; ++j) {
      int r = lhi * 4 + j;
      op[(size_t)r * 1024 + dt * 16 + l15] = (_Float16)o[dt][j];
    }
}

// ====== 256x256 GEMM, cluster-pipelined reads + true double-buffer ======
// A [M][K] f16, Bt [N][K] f16. BK=64, 512 thr = 8 waves (2Mx4N), wave C = 128x64.
// LDS: 2 bufs x (A 32KB + B 32KB). During tile t we stage tile t+1 into the OTHER
// buffer -> ONE vmcnt(0)+barrier per tile, NO intra-tile barriers, no slice calendar.
// 8 clusters of 8 MFMA16 per tile; each cluster's ds_reads are issued ONE CLUSTER
// AHEAD so LDS service overlaps the MFMA pipe. Compiler emits minimal counted
// lgkmcnt per use (m97 evidence) -> partial waits for free, no inline-asm lgkm.
// Safety: every ds_read is consumed by an MFMA before the tile-end barrier (lgkm
// drained); stages only touch the other buffer, whose reads finished a tile ago.
// Swizzle: R8-verified conflict-free (store chunk c^(r&7); pre-swizzled global
// source; INT-offset reads cs0/cs1 - no pointer bit-ops, R7 lesson).
template <int FINAL>
__global__ __launch_bounds__(512, 2) void k_gemm7(const _Float16* __restrict__ A,
                                                  const _Float16* __restrict__ Bt,
                                                  void* __restrict__ Cout,
                                                  const float* __restrict__ bias,
                                                  int M, int N, int K) {
  __shared__ __align__(16) char lds[131072];
  const int t = threadIdx.x, wid = t >> 6, lane = t & 63;
  const int wr = wid >> 2, wc = wid & 3;  // 2M x 4N wave grid
  const int l15 = lane & 15, lhi = lane >> 4;

  // T1: bijective XCD swizzle (nwg % 8 == 0)
  int nwg = gridDim.x, bid = blockIdx.x;
  int wg = ((nwg & 7) == 0) ? ((bid & 7) * (nwg >> 3) + (bid >> 3)) : bid;
  const int nTN = N >> 8;
  const int tm = wg / nTN, tn = wg % nTN;

  const _Float16* Ag = A + (size_t)tm * 256 * K;
  const _Float16* Bg = Bt + (size_t)tn * 256 * K;
  const size_t stg = (size_t)(wid * 8 + (lane >> 3)) * K +
                     (size_t)(((lane & 7) ^ ((lane >> 3) & 7)) * 8);
  const int dstg = wid * 1024;  // linear wave dest (HW adds lane*16)

  // read swizzle as int offsets: chunk(kk) = (kk*4 + lhi) ^ (l15&7)
  const int x7 = l15 & 7;
  const int cs0 = (lhi ^ x7) << 4;
  const int cs1 = ((4 + lhi) ^ x7) << 4;
  const int aoff = wr * 16384 + l15 * 128;
  const int boff = 32768 + wc * 8192 + l15 * 128;

  f32x4 acc[8][4];
#pragma unroll
  for (int i = 0; i < 8; ++i)
#pragma unroll
    for (int j = 0; j < 4; ++j) acc[i][j] = f32x4{0.f, 0.f, 0.f, 0.f};
  f16x8 a0k0[4], a0k1[4], a1k0[4], a1k1[4];
  f16x8 b00[2], b01[2], b10[2], b11[2];

#define STG_A(T, RB) load_lds16(Ag + stg + (size_t)(RB) * K + (T) * 64, \
                                lds + ((T) & 1) * 65536 + (RB) * 128 + dstg)
#define STG_B(T, RB) load_lds16(Bg + stg + (size_t)(RB) * K + (T) * 64, \
                                lds + ((T) & 1) * 65536 + 32768 + (RB) * 128 + dstg)
#define STG_TILE(T) { STG_A(T, 0); STG_A(T, 64); STG_A(T, 128); STG_A(T, 192);  \
                      STG_B(T, 0); STG_B(T, 64); STG_B(T, 128); STG_B(T, 192); }
#define RDA(DST, BUF, MH, CS) { const int p_ = (BUF) * 65536 + aoff + (MH) * 8192; \
    _Pragma("unroll") for (int mf = 0; mf < 4; ++mf)                               \
      DST[mf] = *(const f16x8*)&lds[p_ + mf * 2048 + (CS)]; }
#define RDB(DST, BUF, NH, CS) { const int q_ = (BUF) * 65536 + boff + (NH) * 4096; \
    _Pragma("unroll") for (int nf = 0; nf < 2; ++nf)                               \
      DST[nf] = *(const f16x8*)&lds[q_ + nf * 2048 + (CS)]; }
#define MMC(MH, NH, AR, BR) { __builtin_amdgcn_s_setprio(1);                       \
    _Pragma("unroll") for (int mf = 0; mf < 4; ++mf)                               \
      _Pragma("unroll") for (int nf = 0; nf < 2; ++nf)                             \
        acc[(MH)*4+mf][(NH)*2+nf] = MFMA16(AR[mf], BR[nf],                         \
                                           acc[(MH)*4+mf][(NH)*2+nf]);             \
    __builtin_amdgcn_s_setprio(0); }
#define VM0 asm volatile("s_waitcnt vmcnt(0)" ::: "memory")
#define BAR __builtin_amdgcn_s_barrier()

  // One tile: publish current buf, burst-stage next tile into other buf, then
  // 8 clusters with reads issued one cluster ahead.
#define TILE(BUF, T, STG_ON)                                                       \
  {                                                                                \
    VM0; BAR;                                                                      \
    RDA(a0k0, BUF, 0, cs0); RDB(b00, BUF, 0, cs0);                                 \
    RDB(b10, BUF, 1, cs0);                                                         \
    if (STG_ON) STG_TILE((T) + 1);                                                 \
    MMC(0, 0, a0k0, b00);                                                          \
    RDA(a1k0, BUF, 1, cs0); MMC(0, 1, a0k0, b10);                                  \
    RDA(a1k1, BUF, 1, cs1); MMC(1, 1, a1k0, b10);                                  \
    RDB(b01, BUF, 0, cs1);  MMC(1, 0, a1k0, b00);                                  \
    RDB(b11, BUF, 1, cs1);  MMC(1, 0, a1k1, b01);                                  \
    RDA(a0k1, BUF, 0, cs1); MMC(1, 1, a1k1, b11);                                  \
    MMC(0, 1, a0k1, b11);                                                          \
    MMC(0, 0, a0k1, b01);                                                          \
  }

  const int nT = K >> 6;  // 16 for K=1024 (even, >= 4)

  STG_TILE(0);  // prologue: tile 0 -> buf0

  for (int i = 0; i < (nT >> 1) - 1; ++i) {
    TILE(0, 2 * i, true);
    TILE(1, 2 * i + 1, true);
  }
  TILE(0, nT - 2, true);   // stages tile nT-1 -> buf1
  TILE(1, nT - 1, false);  // last tile: nothing to stage

  // ---- C write: 16x16 C-layout col = l15, row = lhi*4 + reg (verified m89)
  const long rbase = (long)tm * 256 + wr * 128;
  const int cbase = tn * 256 + wc * 64;
#pragma unroll
  for (int mf = 0; mf < 8; ++mf)
#pragma unroll
    for (int nf = 0; nf < 4; ++nf) {
      int c = cbase + nf * 16 + l15;
      float bv = FINAL ? bias[c] : 0.f;
#pragma unroll
      for (int j = 0; j < 4; ++j) {
        long r = rbase + mf * 16 + lhi * 4 + j;
        float v = acc[mf][nf][j];
        if (FINAL) ((float*)Cout)[r * N + c] = v + bv;
        else ((_Float16*)Cout)[r * N + c] = (_Float16)v;
      }
    }
#undef STG_A
#undef STG_B
#undef STG_TILE
#undef RDA
#undef RDB
#undef MMC
#undef TILE
#undef VM0
#undef BAR
}

extern "C" void kernel_launch(void* const* d_in, const int* in_sizes, int n_in,
                              void* d_out, int out_size, void* d_ws, size_t ws_size,
                              hipStream_t stream) {
  const float* x   = (const float*)d_in[0];
  const float* ctx = (const float*)d_in[1];
  const float* Wq  = (const float*)d_in[2];
  const float* Wk  = (const float*)d_in[3];
  const float* Wv  = (const float*)d_in[4];
  const float* Wo  = (const float*)d_in[5];
  const float* bo  = (const float*)d_in[6];

  char* ws = (char*)d_ws;
  _Float16* xh   = (_Float16*)(ws + 0);           // [32768][1024] x-f16; later attnOut
  _Float16* Wqt  = (_Float16*)(ws + 67108864);    // [1024][1024]
  _Float16* Wkt  = (_Float16*)(ws + 69206016);    // [1024][768]
  _Float16* Wvt  = (_Float16*)(ws + 70778880);    // [1024][768]
  _Float16* Wot  = (_Float16*)(ws + 72351744);    // [1024][1024]
  _Float16* ctxh = (_Float16*)(ws + 74448896);    // [616][768]
  _Float16* Kg   = (_Float16*)(ws + 75395072);    // [128][77][64]
  _Float16* Vtg  = (_Float16*)(ws + 76656640);    // [128][64][128]
  _Float16* Qh   = (_Float16*)d_out;              // [32768][1024] f16 scratch in d_out

  k_cvt16<<<4096, 256, 0, stream>>>(x, xh, 33554432 / 8);
  k_cvt16<<<231, 256, 0, stream>>>(ctx, ctxh, 473088 / 8);
  k_transpose<<<dim3(16, 16), 256, 0, stream>>>(Wq, Wqt, 1024, 1024);
  k_transpose<<<dim3(16, 12), 256, 0, stream>>>(Wk, Wkt, 768, 1024);
  k_transpose<<<dim3(16, 12), 256, 0, stream>>>(Wv, Wvt, 768, 1024);
  k_transpose<<<dim3(16, 16), 256, 0, stream>>>(Wo, Wot, 1024, 1024);
  hipMemsetAsync(Vtg, 0, 2097152, stream);
  k_kvproj<<<dim3(39, 64), 64, 0, stream>>>(ctxh, Wkt, Wvt, Kg, Vtg);
  // GEMM1: Q projection -> d_out (f16 scratch); grid 512 (%8==0 for T1)
  k_gemm7<0><<<dim3(512), dim3(512), 0, stream>>>(xh, Wqt, (void*)Qh, nullptr, 32768, 1024, 1024);
  // attention: reads Qh (d_out), writes attnOut -> xh
  k_attn<<<dim3(64, 128), 256, 0, stream>>>(Qh, Kg, Vtg, xh);
  // GEMM2: O projection + bias -> d_out (f32)
  k_gemm7<1><<<dim3(512), dim3(512), 0, stream>>>(xh, Wot, d_out, bo, 32768, 1024, 1024);
}